// Round 1
// baseline (87.077 us; speedup 1.0000x reference)
//
#include <hip/hip_runtime.h>
#include <math.h>

// SVD-based rigid registration: B=4096 batches of N=2048 weighted 3D point pairs.
// Stage 1: per-batch weighted moments (W, St[3], Ss[3], M[9]) in one coalesced pass.
// Stage 2: 3x3 polar decomposition via Jacobi eigen of A^T A (double), R = A (A^T A)^{-1/2},
//          which equals U @ Vh of the reference's SVD.

constexpr int BN      = 2048;  // points per batch
constexpr int THREADS = 256;
constexpr int PPT     = 4;     // points per thread per iteration (12 floats = 3 x float4)
constexpr int ITERS   = BN / (THREADS * PPT);  // 2

__global__ __launch_bounds__(THREADS) void svdreg_kernel(
    const float* __restrict__ target,
    const float* __restrict__ source,
    const float* __restrict__ weights,
    float* __restrict__ out)
{
    const int b   = blockIdx.x;
    const int tid = threadIdx.x;
    const float* tb = target  + (size_t)b * BN * 3;
    const float* sb = source  + (size_t)b * BN * 3;
    const float* wb = weights + (size_t)b * BN;

    // acc layout: [0]=W, [1..3]=St (sum w*t), [4..6]=Ss (sum w*s),
    //             [7..15]=M[i][j] = sum w * t_i * s_j  (row-major)
    float acc[16];
#pragma unroll
    for (int i = 0; i < 16; ++i) acc[i] = 0.f;

#pragma unroll
    for (int it = 0; it < ITERS; ++it) {
        const int p = (tid + it * THREADS) * PPT;           // point index, multiple of 4
        const float4* t4 = reinterpret_cast<const float4*>(tb + (size_t)p * 3);
        const float4* s4 = reinterpret_cast<const float4*>(sb + (size_t)p * 3);
        float4 t0 = t4[0], t1 = t4[1], t2 = t4[2];
        float4 s0 = s4[0], s1 = s4[1], s2 = s4[2];
        float4 w4 = *reinterpret_cast<const float4*>(wb + p);

        // de-swizzle 12 floats -> 4 points of (x,y,z)
        float tx[4] = {t0.x, t0.w, t1.z, t2.y};
        float ty[4] = {t0.y, t1.x, t1.w, t2.z};
        float tz[4] = {t0.z, t1.y, t2.x, t2.w};
        float sx[4] = {s0.x, s0.w, s1.z, s2.y};
        float sy[4] = {s0.y, s1.x, s1.w, s2.z};
        float sz[4] = {s0.z, s1.y, s2.x, s2.w};
        float ww[4] = {w4.x, w4.y, w4.z, w4.w};

#pragma unroll
        for (int j = 0; j < 4; ++j) {
            float w = ww[j];
            acc[0] += w;
            float wtx = w * tx[j], wty = w * ty[j], wtz = w * tz[j];
            acc[1] += wtx;  acc[2] += wty;  acc[3] += wtz;
            acc[4] += w * sx[j]; acc[5] += w * sy[j]; acc[6] += w * sz[j];
            acc[7]  += wtx * sx[j]; acc[8]  += wtx * sy[j]; acc[9]  += wtx * sz[j];
            acc[10] += wty * sx[j]; acc[11] += wty * sy[j]; acc[12] += wty * sz[j];
            acc[13] += wtz * sx[j]; acc[14] += wtz * sy[j]; acc[15] += wtz * sz[j];
        }
    }

    // 64-lane butterfly reduce each accumulator
#pragma unroll
    for (int i = 0; i < 16; ++i) {
#pragma unroll
        for (int off = 32; off > 0; off >>= 1)
            acc[i] += __shfl_xor(acc[i], off);
    }

    __shared__ float part[THREADS / 64][16];
    const int wave = tid >> 6;
    const int lane = tid & 63;
    if (lane == 0) {
#pragma unroll
        for (int i = 0; i < 16; ++i) part[wave][i] = acc[i];
    }
    __syncthreads();

    if (tid == 0) {
        double v[16];
#pragma unroll
        for (int i = 0; i < 16; ++i)
            v[i] = (double)part[0][i] + (double)part[1][i]
                 + (double)part[2][i] + (double)part[3][i];

        const double W  = v[0];
        const double Wd = W + 1e-8;
        double St[3] = {v[1], v[2], v[3]};
        double Ss[3] = {v[4], v[5], v[6]};
        double mt[3], ms[3];
        for (int i = 0; i < 3; ++i) { mt[i] = St[i] / Wd; ms[i] = Ss[i] / Wd; }

        // cross-covariance A
        double A[3][3];
        for (int i = 0; i < 3; ++i)
            for (int j = 0; j < 3; ++j)
                A[i][j] = v[7 + i * 3 + j] - mt[i] * Ss[j] - ms[j] * St[i] + mt[i] * ms[j] * W;

        // S = A^T A (symmetric PSD)
        double Smat[3][3];
        for (int i = 0; i < 3; ++i)
            for (int j = 0; j < 3; ++j) {
                double s = 0.0;
                for (int k = 0; k < 3; ++k) s += A[k][i] * A[k][j];
                Smat[i][j] = s;
            }

        // cyclic Jacobi eigendecomposition: S = V D V^T
        double V[3][3] = {{1,0,0},{0,1,0},{0,0,1}};
        for (int sweep = 0; sweep < 12; ++sweep) {
            for (int pi = 0; pi < 2; ++pi) {
                for (int qi = pi + 1; qi < 3; ++qi) {
                    double apq = Smat[pi][qi];
                    if (fabs(apq) < 1e-300) continue;
                    double app = Smat[pi][pi], aqq = Smat[qi][qi];
                    double theta = (aqq - app) / (2.0 * apq);
                    double tt = (theta >= 0.0 ? 1.0 : -1.0) /
                                (fabs(theta) + sqrt(theta * theta + 1.0));
                    double c = 1.0 / sqrt(tt * tt + 1.0);
                    double s = tt * c;
                    // right-mult by G (cols), left-mult by G^T (rows), V <- V G
                    for (int k = 0; k < 3; ++k) {
                        double skp = Smat[k][pi], skq = Smat[k][qi];
                        Smat[k][pi] = c * skp - s * skq;
                        Smat[k][qi] = s * skp + c * skq;
                    }
                    for (int k = 0; k < 3; ++k) {
                        double spk = Smat[pi][k], sqk = Smat[qi][k];
                        Smat[pi][k] = c * spk - s * sqk;
                        Smat[qi][k] = s * spk + c * sqk;
                    }
                    for (int k = 0; k < 3; ++k) {
                        double vkp = V[k][pi], vkq = V[k][qi];
                        V[k][pi] = c * vkp - s * vkq;
                        V[k][qi] = s * vkp + c * vkq;
                    }
                }
            }
        }

        // R = A * V * D^{-1/2} * V^T  (== U @ Vh of SVD(A))
        double inv_s[3];
        for (int i = 0; i < 3; ++i) {
            double d = Smat[i][i];
            d = (d > 1e-300) ? d : 1e-300;
            inv_s[i] = 1.0 / sqrt(d);
        }
        double P[3][3];
        for (int i = 0; i < 3; ++i)
            for (int j = 0; j < 3; ++j) {
                double s = 0.0;
                for (int k = 0; k < 3; ++k) s += V[i][k] * inv_s[k] * V[j][k];
                P[i][j] = s;
            }
        double R[3][3];
        for (int i = 0; i < 3; ++i)
            for (int j = 0; j < 3; ++j) {
                double s = 0.0;
                for (int k = 0; k < 3; ++k) s += A[i][k] * P[k][j];
                R[i][j] = s;
            }
        double tvec[3];
        for (int i = 0; i < 3; ++i) {
            double s = mt[i];
            for (int k = 0; k < 3; ++k) s -= R[i][k] * ms[k];
            tvec[i] = s;
        }

        float* o = out + (size_t)b * 16;
        o[0]  = (float)R[0][0]; o[1]  = (float)R[0][1]; o[2]  = (float)R[0][2]; o[3]  = (float)tvec[0];
        o[4]  = (float)R[1][0]; o[5]  = (float)R[1][1]; o[6]  = (float)R[1][2]; o[7]  = (float)tvec[1];
        o[8]  = (float)R[2][0]; o[9]  = (float)R[2][1]; o[10] = (float)R[2][2]; o[11] = (float)tvec[2];
        o[12] = 0.f; o[13] = 0.f; o[14] = 0.f; o[15] = 1.f;
    }
}

extern "C" void kernel_launch(void* const* d_in, const int* in_sizes, int n_in,
                              void* d_out, int out_size, void* d_ws, size_t ws_size,
                              hipStream_t stream) {
    const float* target  = (const float*)d_in[0];
    const float* source  = (const float*)d_in[1];
    const float* weights = (const float*)d_in[2];
    float* out = (float*)d_out;

    const int B = in_sizes[2] / BN;  // weights flat = B*N
    svdreg_kernel<<<B, THREADS, 0, stream>>>(target, source, weights, out);
}

// Round 2
// 43.573 us; speedup vs baseline: 1.9984x; 1.9984x over previous
//
#include <hip/hip_runtime.h>
#include <math.h>

// SVD rigid registration, split in two:
//  K1: per-batch weighted moments (W, St[3], Ss[3], M[9]) — one 64-lane wave
//      per batch, 32 points/thread, butterfly reduce, 16 floats -> d_ws.
//  K2: one THREAD per batch: cov assembly (double) + det-scaled Newton polar
//      iteration (R = U@Vh, no SVD/sqrt), writes the 4x4 T.

constexpr int BN      = 2048;   // points per batch
constexpr int THREADS = 256;    // 4 waves -> 4 batches per block in K1

__global__ __launch_bounds__(THREADS) void moments_kernel(
    const float* __restrict__ target,
    const float* __restrict__ source,
    const float* __restrict__ weights,
    float* __restrict__ ws)
{
    const int lane = threadIdx.x & 63;
    const int b    = (blockIdx.x * THREADS + threadIdx.x) >> 6;  // wave id = batch

    const float4* t4 = reinterpret_cast<const float4*>(target + (size_t)b * BN * 3);
    const float4* s4 = reinterpret_cast<const float4*>(source + (size_t)b * BN * 3);
    const float4* w4 = reinterpret_cast<const float4*>(weights + (size_t)b * BN);

    // [0]=W, [1..3]=sum w*t, [4..6]=sum w*s, [7..15]=sum w*t_i*s_j (row-major)
    float acc[16];
#pragma unroll
    for (int i = 0; i < 16; ++i) acc[i] = 0.f;

#pragma unroll
    for (int it = 0; it < BN / (64 * 4); ++it) {          // 8 iterations x 4 points
        const int g  = it * 64 + lane;                    // float4-group index
        float4 t0 = t4[g * 3 + 0], t1 = t4[g * 3 + 1], t2 = t4[g * 3 + 2];
        float4 s0 = s4[g * 3 + 0], s1 = s4[g * 3 + 1], s2 = s4[g * 3 + 2];
        float4 wv = w4[g];

        float tx[4] = {t0.x, t0.w, t1.z, t2.y};
        float ty[4] = {t0.y, t1.x, t1.w, t2.z};
        float tz[4] = {t0.z, t1.y, t2.x, t2.w};
        float sx[4] = {s0.x, s0.w, s1.z, s2.y};
        float sy[4] = {s0.y, s1.x, s1.w, s2.z};
        float sz[4] = {s0.z, s1.y, s2.x, s2.w};
        float ww[4] = {wv.x, wv.y, wv.z, wv.w};

#pragma unroll
        for (int j = 0; j < 4; ++j) {
            float w = ww[j];
            acc[0] += w;
            float wtx = w * tx[j], wty = w * ty[j], wtz = w * tz[j];
            acc[1] += wtx;  acc[2] += wty;  acc[3] += wtz;
            acc[4] += w * sx[j]; acc[5] += w * sy[j]; acc[6] += w * sz[j];
            acc[7]  += wtx * sx[j]; acc[8]  += wtx * sy[j]; acc[9]  += wtx * sz[j];
            acc[10] += wty * sx[j]; acc[11] += wty * sy[j]; acc[12] += wty * sz[j];
            acc[13] += wtz * sx[j]; acc[14] += wtz * sy[j]; acc[15] += wtz * sz[j];
        }
    }

#pragma unroll
    for (int i = 0; i < 16; ++i) {
#pragma unroll
        for (int off = 32; off > 0; off >>= 1)
            acc[i] += __shfl_xor(acc[i], off);
    }

    if (lane == 0) {
        float4* o = reinterpret_cast<float4*>(ws + (size_t)b * 16);
        o[0] = make_float4(acc[0],  acc[1],  acc[2],  acc[3]);
        o[1] = make_float4(acc[4],  acc[5],  acc[6],  acc[7]);
        o[2] = make_float4(acc[8],  acc[9],  acc[10], acc[11]);
        o[3] = make_float4(acc[12], acc[13], acc[14], acc[15]);
    }
}

__global__ __launch_bounds__(64) void polar_kernel(
    const float* __restrict__ ws,
    float* __restrict__ out,
    int B)
{
    const int b = blockIdx.x * 64 + threadIdx.x;
    if (b >= B) return;

    const float4* i4 = reinterpret_cast<const float4*>(ws + (size_t)b * 16);
    float4 p0 = i4[0], p1 = i4[1], p2 = i4[2], p3 = i4[3];
    double v[16] = {p0.x, p0.y, p0.z, p0.w,  p1.x, p1.y, p1.z, p1.w,
                    p2.x, p2.y, p2.z, p2.w,  p3.x, p3.y, p3.z, p3.w};

    const double W  = v[0];
    const double Wd = W + 1e-8;
    double St[3] = {v[1], v[2], v[3]};
    double Ss[3] = {v[4], v[5], v[6]};
    double mt[3], ms[3];
#pragma unroll
    for (int i = 0; i < 3; ++i) { mt[i] = St[i] / Wd; ms[i] = Ss[i] / Wd; }

    double A[3][3];
#pragma unroll
    for (int i = 0; i < 3; ++i)
#pragma unroll
        for (int j = 0; j < 3; ++j)
            A[i][j] = v[7 + i * 3 + j] - mt[i] * Ss[j] - ms[j] * St[i] + mt[i] * ms[j] * W;

    // Newton polar iteration with determinant scaling:
    //   X <- 0.5 * (mu*X + (1/(mu*det)) * cof(X)),  cof(X) = det(X)*X^{-T}
    // Converges to the orthogonal polar factor U@Vh of A.
    double X[3][3];
#pragma unroll
    for (int i = 0; i < 3; ++i)
#pragma unroll
        for (int j = 0; j < 3; ++j) X[i][j] = A[i][j];

#pragma unroll
    for (int iter = 0; iter < 12; ++iter) {
        double C[3][3];
        C[0][0] = X[1][1]*X[2][2] - X[1][2]*X[2][1];
        C[0][1] = X[1][2]*X[2][0] - X[1][0]*X[2][2];
        C[0][2] = X[1][0]*X[2][1] - X[1][1]*X[2][0];
        C[1][0] = X[0][2]*X[2][1] - X[0][1]*X[2][2];
        C[1][1] = X[0][0]*X[2][2] - X[0][2]*X[2][0];
        C[1][2] = X[0][1]*X[2][0] - X[0][0]*X[2][1];
        C[2][0] = X[0][1]*X[1][2] - X[0][2]*X[1][1];
        C[2][1] = X[0][2]*X[1][0] - X[0][0]*X[1][2];
        C[2][2] = X[0][0]*X[1][1] - X[0][1]*X[1][0];
        double det = X[0][0]*C[0][0] + X[0][1]*C[0][1] + X[0][2]*C[0][2];
        double ad  = fabs(det);
        if (!(ad > 1e-300)) { det = (det >= 0.0) ? 1e-300 : -1e-300; ad = 1e-300; }

        double mu = 1.0;
        if (iter < 9) {  // det scaling accelerates the spread-out phase
            float adf = (float)ad;
            if (adf > 0.f && isfinite(adf))
                mu = (double)exp2f(-log2f(adf) * (1.0f / 3.0f));
        }
        double k1 = 0.5 * mu;
        double k2 = 0.5 / (mu * det);
#pragma unroll
        for (int i = 0; i < 3; ++i)
#pragma unroll
            for (int j = 0; j < 3; ++j)
                X[i][j] = k1 * X[i][j] + k2 * C[i][j];
    }

    double tvec[3];
#pragma unroll
    for (int i = 0; i < 3; ++i) {
        double s = mt[i];
#pragma unroll
        for (int k = 0; k < 3; ++k) s -= X[i][k] * ms[k];
        tvec[i] = s;
    }

    float4* o = reinterpret_cast<float4*>(out + (size_t)b * 16);
    o[0] = make_float4((float)X[0][0], (float)X[0][1], (float)X[0][2], (float)tvec[0]);
    o[1] = make_float4((float)X[1][0], (float)X[1][1], (float)X[1][2], (float)tvec[1]);
    o[2] = make_float4((float)X[2][0], (float)X[2][1], (float)X[2][2], (float)tvec[2]);
    o[3] = make_float4(0.f, 0.f, 0.f, 1.f);
}

extern "C" void kernel_launch(void* const* d_in, const int* in_sizes, int n_in,
                              void* d_out, int out_size, void* d_ws, size_t ws_size,
                              hipStream_t stream) {
    const float* target  = (const float*)d_in[0];
    const float* source  = (const float*)d_in[1];
    const float* weights = (const float*)d_in[2];
    float* out = (float*)d_out;
    float* ws  = (float*)d_ws;

    const int B = in_sizes[2] / BN;  // weights flat = B*N

    moments_kernel<<<B / (THREADS / 64), THREADS, 0, stream>>>(target, source, weights, ws);
    polar_kernel<<<(B + 63) / 64, 64, 0, stream>>>(ws, out, B);
}